// Round 7
// baseline (24077.950 us; speedup 1.0000x reference)
//
#include <hip/hip_runtime.h>
#include <hip/hip_bf16.h>
#include <math.h>

typedef __hip_bfloat16 bf16;

// ---------------------------------------------------------------------------
// flag: 1 = fp32 inputs, 0 = packed-bf16 inputs (kept for safety; fp32 proven)
// ---------------------------------------------------------------------------
__device__ __forceinline__ float ldin(const void* p, long i, int f) {
    if (f) return ((const float*)p)[i];
    unsigned short u = ((const unsigned short*)p)[i];
    return __uint_as_float(((unsigned)u) << 16);
}

__global__ void probe_small(const void* __restrict__ in6, const void* __restrict__ in7,
                            float* __restrict__ qgc, float* __restrict__ lpc,
                            int* __restrict__ flag, int H) {
    unsigned w = *(const unsigned*)in6;
    int f = ((w & 0xFFFFu) == 0u) ? 1 : 0;
    if (threadIdx.x == 0) *flag = f;
    if ((int)threadIdx.x < H) {
        qgc[threadIdx.x] = ldin(in6, threadIdx.x, f);
        lpc[threadIdx.x] = ldin(in7, threadIdx.x, f);
    }
}

// ---------------------------------------------------------------------------
// Naive GEMM C[M,N] = A[M,K] * B[N,K]^T, A and B raw inputs (flagged).
// ---------------------------------------------------------------------------
__global__ void ngemm_in(const void* __restrict__ A, const void* __restrict__ B,
                         float* __restrict__ C, int M, int N, int K,
                         const int* __restrict__ flag) {
    const long idx = (long)blockIdx.x * 256 + threadIdx.x;
    if (idx >= (long)M * N) return;
    const int f = *flag;
    const int row = (int)(idx / N);
    const int col = (int)(idx - (long)row * N);
    const long ar = (long)row * K, br = (long)col * K;
    float acc = 0.f;
    for (int k = 0; k < K; ++k) acc += ldin(A, ar + k, f) * ldin(B, br + k, f);
    C[idx] = acc;
}

// A internal fp32, B raw input (flagged). OUTPUT FP32 (the round-7 fix).
__global__ void ngemm_mix(const float* __restrict__ A, const void* __restrict__ B,
                          float* __restrict__ C, int M, int N, int K,
                          const int* __restrict__ flag) {
    const long idx = (long)blockIdx.x * 256 + threadIdx.x;
    if (idx >= (long)M * N) return;
    const int f = *flag;
    const int row = (int)(idx / N);
    const int col = (int)(idx - (long)row * N);
    const float* a = A + (long)row * K;
    const long br = (long)col * K;
    float acc = 0.f;
    for (int k = 0; k < K; ++k) acc += a[k] * ldin(B, br + k, f);
    C[idx] = acc;
}

// ---------------------------------------------------------------------------
// Postproc: one thread per (token, unit). unit<H: Q rms+rotary+gain;
// H..H+KVH-1: K rms+rotary; H+KVH..: V sigmoid gate.
// ---------------------------------------------------------------------------
__global__ void postproc_n(float* __restrict__ Qp, float* __restrict__ Kp,
                           float* __restrict__ Vp, const float* __restrict__ Gp,
                           const float* __restrict__ qgain,
                           int S, int DIM, int KVDIM, int H, int KVH, int HD,
                           const int* __restrict__ flag) {
    const int id = blockIdx.x * 64 + threadIdx.x;
    const int units = H + 2 * KVH;
    if (id >= S * units) return;
    const int s = id / units;
    const int unit = id - s * units;
    const float eps = (*flag) ? 1.1920928955078125e-7f : 0.0078125f;
    if (unit < H + KVH) {
        float* p = (unit < H) ? (Qp + (long)s * DIM + unit * HD)
                              : (Kp + (long)s * KVDIM + (unit - H) * HD);
        const float gain = (unit < H) ? qgain[unit] : 1.0f;
        float buf[128];
        float ss = 0.f;
        for (int d = 0; d < HD; ++d) { buf[d] = p[d]; ss += buf[d] * buf[d]; }
        const float inv = rsqrtf(ss / (float)HD + eps);
        const float radius = 1.0f / (1.0f + 0.01f * (float)s);
        const int half = HD / 2;
        for (int i = 0; i < half; ++i) {
            const float x1 = buf[i] * inv, x2 = buf[i + half] * inv;
            const float af  = (float)(((double)(2 * i) / (double)HD) * 3.14159265358979323846);
            const float ang = (float)s * af;
            const float c  = radius * (float)cos((double)ang);
            const float sn = radius * (float)sin((double)ang);
            p[i]        = (x1 * c + x2 * sn) * gain;
            p[i + half] = (-x1 * sn + x2 * c) * gain;
        }
    } else {
        const int hh = unit - H - KVH;
        float* v = Vp + (long)s * KVDIM + hh * HD;
        const float* g = Gp + (long)s * KVDIM + hh * HD;
        for (int d = 0; d < HD; ++d)
            v[d] = v[d] / (1.0f + expf(-g[d]));
    }
}

// ---------------------------------------------------------------------------
// Exact two-pass attention oracle: one 64-thread block per (s, h, half).
// ---------------------------------------------------------------------------
__global__ void attn_n(const float* __restrict__ Qp, const float* __restrict__ Kp,
                       const float* __restrict__ Vp, float* __restrict__ Ao,
                       int S, int DIM, int KVDIM, int HD, int rep, float scale) {
    extern __shared__ float sc[];
    __shared__ float qs[128];
    __shared__ float red[2];
    const int s = blockIdx.x, h = blockIdx.y, half = blockIdx.z;
    const int tid = threadIdx.x;
    const int kvh = h / rep;
    const int hw = HD / 2;
    if (tid < hw) qs[tid] = Qp[(long)s * DIM + h * HD + half * hw + tid];
    __syncthreads();
    for (int j = tid; j <= s; j += 64) {
        const float* k = Kp + (long)j * KVDIM + kvh * HD + half * hw;
        float acc = 0.f;
        for (int d = 0; d < hw; ++d) acc += qs[d] * k[d];
        sc[j] = acc * scale;
    }
    __syncthreads();
    if (tid == 0) {
        float m = sc[0];
        for (int j = 1; j <= s; ++j) m = fmaxf(m, sc[j]);
        red[0] = m;
    }
    __syncthreads();
    const float m = red[0];
    for (int j = tid; j <= s; j += 64) sc[j] = expf(sc[j] - m);
    __syncthreads();
    if (tid == 0) {
        float l = 0.f;
        for (int j = 0; j <= s; ++j) l += sc[j];
        red[1] = l;
    }
    __syncthreads();
    const float linv = 1.0f / red[1];
    if (tid < hw) {
        float o = 0.f;
        for (int j = 0; j <= s; ++j)
            o += sc[j] * Vp[(long)j * KVDIM + kvh * HD + half * hw + tid];
        Ao[(long)s * DIM + h * HD + half * hw + tid] = o * linv;
    }
}

// ---------------------------------------------------------------------------
// Combine: y[..,0:half]=a1-lam*a2 ; y[..,half:HD]=a1+lam*a2
// ---------------------------------------------------------------------------
__global__ void combine_n(const float* __restrict__ A, const float* __restrict__ lam_p,
                          float* __restrict__ Y, int S, int DIM, int HD) {
    const long idx = (long)blockIdx.x * 256 + threadIdx.x;
    if (idx >= (long)S * DIM) return;
    const int s = (int)(idx / DIM);
    const int c = (int)(idx - (long)s * DIM);
    const int hh = c / HD;
    const int d = c - hh * HD;
    const int half = HD / 2;
    const float* base = A + (long)s * DIM + hh * HD;
    const float lam = lam_p[hh];
    float y;
    if (d < half) y = base[d]        - lam * base[d + half];
    else          y = base[d - half] + lam * base[d];
    Y[idx] = y;
}

// ---------------------------------------------------------------------------
extern "C" void kernel_launch(void* const* d_in, const int* in_sizes, int n_in,
                              void* d_out, int out_size, void* d_ws, size_t ws_size,
                              hipStream_t stream) {
    // ---- runtime shape derivation from in_sizes ----
    int DIM = 1024;
    {
        long n1 = in_sizes[1];
        int t = (int)lround(sqrt((double)n1));
        if ((long)t * t == n1 && t > 0) DIM = t;
    }
    int S     = (DIM > 0) ? in_sizes[0] / DIM : 2048;
    int KVDIM = (DIM > 0) ? in_sizes[2] / DIM : 256;
    int H     = (in_sizes[6] > 0 && in_sizes[6] <= 256) ? in_sizes[6] : 16;
    if (DIM % H != 0) H = 16;
    int HD  = DIM / H;
    int KVH = (HD > 0) ? KVDIM / HD : 4;
    int rep = (KVH > 0) ? H / KVH : 4;
    int half = HD / 2;
    float scale = (float)(1.0 / sqrt((double)half));

    const void* x  = d_in[0];
    const void* Wq = d_in[1];
    const void* Wk = d_in[2];
    const void* Wv = d_in[3];
    const void* Wg = d_in[4];
    const void* Wo = d_in[5];
    float* out = (float*)d_out;   // OUTPUT IS FP32 (reference output dtype)

    char* ws = (char*)d_ws;
    const long qN  = (long)S * DIM;
    const long kvN = (long)S * KVDIM;
    float* Qp  = (float*)ws;
    float* Kp  = Qp + qN;
    float* Vp  = Kp + kvN;
    float* Gp  = Vp + kvN;
    float* Ao  = Gp + kvN;
    float* Y   = Qp;              // overlays Qp (dead after attention)
    float* qgc = Ao + qN;
    float* lpc = qgc + 64;
    int*  flag = (int*)(lpc + 64);

    // 0. Probe dtype, stage q_gain/lambda as fp32
    probe_small<<<1, 64, 0, stream>>>(d_in[6], d_in[7], qgc, lpc, flag, H);

    // 1. Projections
    {
        long n = (long)S * DIM;
        ngemm_in<<<(int)((n + 255) / 256), 256, 0, stream>>>(x, Wq, Qp, S, DIM, DIM, flag);
        n = (long)S * KVDIM;
        ngemm_in<<<(int)((n + 255) / 256), 256, 0, stream>>>(x, Wk, Kp, S, KVDIM, DIM, flag);
        ngemm_in<<<(int)((n + 255) / 256), 256, 0, stream>>>(x, Wv, Vp, S, KVDIM, DIM, flag);
        ngemm_in<<<(int)((n + 255) / 256), 256, 0, stream>>>(x, Wg, Gp, S, KVDIM, DIM, flag);
    }

    // 2. RMSNorm + polar rotary + gate
    {
        int units = H + 2 * KVH;
        postproc_n<<<(S * units + 63) / 64, 64, 0, stream>>>(
            Qp, Kp, Vp, Gp, qgc, S, DIM, KVDIM, H, KVH, HD, flag);
    }

    // 3. Exact attention per (s, head, half)
    attn_n<<<dim3(S, H, 2), 64, (size_t)S * sizeof(float), stream>>>(
        Qp, Kp, Vp, Ao, S, DIM, KVDIM, HD, rep, scale);

    // 4. Lambda combine
    combine_n<<<(int)(((long)S * DIM + 255) / 256), 256, 0, stream>>>(
        Ao, lpc, Y, S, DIM, HD);

    // 5. Output projection -> FP32 out
    ngemm_mix<<<(int)(((long)S * DIM + 255) / 256), 256, 0, stream>>>(
        Y, Wo, out, S, DIM, DIM, flag);
}

// Round 8
// 1292.010 us; speedup vs baseline: 18.6360x; 18.6360x over previous
//
#include <hip/hip_runtime.h>
#include <hip/hip_bf16.h>
#include <math.h>

#define S_LEN 2048
#define DIM   1024
#define NH    16
#define NKVH  4
#define HD    64
#define KVDIM 256
#define NEG_BIG (-1e30f)

typedef __hip_bfloat16 bf16;

// ---------------------------------------------------------------------------
// GEMM: C[M,N] = A[M,K] * B[N,K]^T.  A,B fp32 row-major (K contiguous).
// 64x64 tile, BK=32, 256 threads, 4x4 microtile. fp32 accumulate.
// ---------------------------------------------------------------------------
__global__ __launch_bounds__(256) void gemm_nt(
    const float* __restrict__ A, const float* __restrict__ B,
    float* __restrict__ C, int M, int N, int K) {
    __shared__ float As[64][36];
    __shared__ float Bs[64][36];
    const int tid = threadIdx.x;
    const int bm = blockIdx.y * 64;
    const int bn = blockIdx.x * 64;
    const int lr = tid >> 2;          // 0..63 staging row
    const int lc = (tid & 3) << 3;    // 0,8,16,24
    const int ty = tid >> 4;          // 0..15
    const int tx = tid & 15;          // 0..15
    float acc[4][4] = {};
    const float* ap = A + (size_t)(bm + lr) * K + lc;
    const float* bp = B + (size_t)(bn + lr) * K + lc;
    for (int k0 = 0; k0 < K; k0 += 32) {
        float4 a0 = *(const float4*)(ap + k0);
        float4 a1 = *(const float4*)(ap + k0 + 4);
        float4 b0 = *(const float4*)(bp + k0);
        float4 b1 = *(const float4*)(bp + k0 + 4);
        *(float4*)&As[lr][lc]     = a0;
        *(float4*)&As[lr][lc + 4] = a1;
        *(float4*)&Bs[lr][lc]     = b0;
        *(float4*)&Bs[lr][lc + 4] = b1;
        __syncthreads();
        #pragma unroll
        for (int kk = 0; kk < 32; kk += 4) {
            float4 a[4], b[4];
            #pragma unroll
            for (int i = 0; i < 4; ++i) a[i] = *(const float4*)&As[ty + 16*i][kk];
            #pragma unroll
            for (int j = 0; j < 4; ++j) b[j] = *(const float4*)&Bs[tx + 16*j][kk];
            #pragma unroll
            for (int i = 0; i < 4; ++i)
                #pragma unroll
                for (int j = 0; j < 4; ++j)
                    acc[i][j] += a[i].x*b[j].x + a[i].y*b[j].y +
                                 a[i].z*b[j].z + a[i].w*b[j].w;
        }
        __syncthreads();
    }
    #pragma unroll
    for (int i = 0; i < 4; ++i) {
        const int row = bm + ty + 16*i;
        #pragma unroll
        for (int j = 0; j < 4; ++j)
            C[(size_t)row * N + bn + tx + 16*j] = acc[i][j];
    }
}

// Fused K/V/G projection (N=256 each): grid.x = 12 (w = bx>>2 picks weight)
__global__ __launch_bounds__(256) void gemm_kvg(
    const float* __restrict__ A, const float* __restrict__ B0,
    const float* __restrict__ B1, const float* __restrict__ B2,
    float* __restrict__ C /* K,V,G contiguous: each S_LEN*KVDIM */) {
    __shared__ float As[64][36];
    __shared__ float Bs[64][36];
    const int tid = threadIdx.x;
    const int w  = blockIdx.x >> 2;
    const int bn = (blockIdx.x & 3) * 64;
    const int bm = blockIdx.y * 64;
    const float* B = (w == 0) ? B0 : (w == 1) ? B1 : B2;
    float* Cw = C + (size_t)w * S_LEN * KVDIM;
    const int K = DIM, N = KVDIM;
    const int lr = tid >> 2;
    const int lc = (tid & 3) << 3;
    const int ty = tid >> 4;
    const int tx = tid & 15;
    float acc[4][4] = {};
    const float* ap = A + (size_t)(bm + lr) * K + lc;
    const float* bp = B + (size_t)(bn + lr) * K + lc;
    for (int k0 = 0; k0 < K; k0 += 32) {
        float4 a0 = *(const float4*)(ap + k0);
        float4 a1 = *(const float4*)(ap + k0 + 4);
        float4 b0 = *(const float4*)(bp + k0);
        float4 b1 = *(const float4*)(bp + k0 + 4);
        *(float4*)&As[lr][lc]     = a0;
        *(float4*)&As[lr][lc + 4] = a1;
        *(float4*)&Bs[lr][lc]     = b0;
        *(float4*)&Bs[lr][lc + 4] = b1;
        __syncthreads();
        #pragma unroll
        for (int kk = 0; kk < 32; kk += 4) {
            float4 a[4], b[4];
            #pragma unroll
            for (int i = 0; i < 4; ++i) a[i] = *(const float4*)&As[ty + 16*i][kk];
            #pragma unroll
            for (int j = 0; j < 4; ++j) b[j] = *(const float4*)&Bs[tx + 16*j][kk];
            #pragma unroll
            for (int i = 0; i < 4; ++i)
                #pragma unroll
                for (int j = 0; j < 4; ++j)
                    acc[i][j] += a[i].x*b[j].x + a[i].y*b[j].y +
                                 a[i].z*b[j].z + a[i].w*b[j].w;
        }
        __syncthreads();
    }
    #pragma unroll
    for (int i = 0; i < 4; ++i) {
        const int row = bm + ty + 16*i;
        #pragma unroll
        for (int j = 0; j < 4; ++j)
            Cw[(size_t)row * N + bn + tx + 16*j] = acc[i][j];
    }
}

// ---------------------------------------------------------------------------
// Postproc: RMSNorm + polar rotary (+q_gain) on Q,K heads; sigmoid gate on V.
// grid (S_LEN, NH + NKVH + NKVH), 64 threads (one wave per token-head).
// ---------------------------------------------------------------------------
__device__ __forceinline__ void rms_rotary(float* p, int s, int lane, float gain) {
    float x = p[lane];
    float ss = x * x;
    #pragma unroll
    for (int o = 32; o > 0; o >>= 1) ss += __shfl_xor(ss, o);
    float n = x * rsqrtf(ss * (1.0f/64.0f) + 1.1920928955078125e-7f);
    float other = __shfl_xor(n, 32);
    int i = lane & 31;
    float af  = (float)(((double)(2*i) / 64.0) * 3.14159265358979323846);
    float ang = (float)s * af;
    float radius = 1.0f / (1.0f + 0.01f * (float)s);
    float c  = radius * (float)cos((double)ang);
    float sn = radius * (float)sin((double)ang);
    float out = n * c + ((lane < 32) ? other * sn : -other * sn);
    p[lane] = out * gain;
}

__global__ __launch_bounds__(64) void postproc(
    float* __restrict__ Qp, float* __restrict__ Kp, float* __restrict__ Vp,
    const float* __restrict__ Gp, const float* __restrict__ qgain) {
    const int s = blockIdx.x;
    const int unit = blockIdx.y;
    const int lane = threadIdx.x;
    if (unit < NH) {
        rms_rotary(Qp + (size_t)s * DIM + unit * HD, s, lane, qgain[unit]);
    } else if (unit < NH + NKVH) {
        rms_rotary(Kp + (size_t)s * KVDIM + (unit - NH) * HD, s, lane, 1.0f);
    } else {
        const int h = unit - NH - NKVH;
        float* v = Vp + (size_t)s * KVDIM + h * HD;
        const float* g = Gp + (size_t)s * KVDIM + h * HD;
        float gv = g[lane];
        v[lane] = v[lane] / (1.0f + __expf(-gv));
    }
}

// ---------------------------------------------------------------------------
// Flash attention over one 32-dim half. Block = 64 threads = 4 q-heads (same
// kv head) x 16 lanes; 2 q-rows per thread. K/V tiles (32 keys) in LDS.
// grid (64 qtiles-of-32 [heavy first], NKVH, 2 halves). All-finite softmax.
// ---------------------------------------------------------------------------
__global__ __launch_bounds__(64) void attn_kernel(
    const float* __restrict__ Qp, const float* __restrict__ Kp,
    const float* __restrict__ Vp, float* __restrict__ Aout) {
    const int qt   = gridDim.x - 1 - blockIdx.x;  // heavy tiles dispatch first
    const int kvh  = blockIdx.y;
    const int half = blockIdx.z;
    const int tid  = threadIdx.x;
    const int wq   = tid >> 4;        // 0..3 -> q head within kv group
    const int l16  = tid & 15;
    const int h    = kvh * 4 + wq;
    const int r0   = qt * 32 + l16;
    const int r1   = r0 + 16;
    __shared__ float Ks[32][32];
    __shared__ float Vs[32][32];
    float q0[32], q1[32];
    const float* q0p = Qp + (size_t)r0 * DIM + h * HD + half * 32;
    const float* q1p = Qp + (size_t)r1 * DIM + h * HD + half * 32;
    #pragma unroll
    for (int d = 0; d < 32; ++d) {
        q0[d] = q0p[d];
        q1[d] = q1p[d];
    }
    float acc0[32] = {}, acc1[32] = {};
    float m0 = NEG_BIG, m1 = NEG_BIG, l0 = 0.f, l1 = 0.f;
    const float scale = 0.17677669529663687f;  // 1/sqrt(32)
    const int jrow = tid >> 1;
    const int jcol = (tid & 1) * 16;
    const int ktiles = qt + 1;
    for (int kb = 0; kb < ktiles; ++kb) {
        const float* kp = Kp + (size_t)(kb*32 + jrow) * KVDIM + kvh * HD + half * 32 + jcol;
        const float* vp = Vp + (size_t)(kb*32 + jrow) * KVDIM + kvh * HD + half * 32 + jcol;
        #pragma unroll
        for (int c = 0; c < 16; c += 4) {
            *(float4*)&Ks[jrow][jcol + c] = *(const float4*)(kp + c);
            *(float4*)&Vs[jrow][jcol + c] = *(const float4*)(vp + c);
        }
        __syncthreads();
        const bool diag = (kb == qt);
        for (int j = 0; j < 32; ++j) {
            float s0 = 0.f, s1 = 0.f;
            #pragma unroll
            for (int d = 0; d < 32; ++d) {
                float kv = Ks[j][d];
                s0 += q0[d] * kv;
                s1 += q1[d] * kv;
            }
            s0 *= scale; s1 *= scale;
            if (diag) {
                if (j > l16)      s0 = NEG_BIG;   // causal mask (finite sentinel)
                if (j > l16 + 16) s1 = NEG_BIG;
            }
            float mn0 = fmaxf(m0, s0);
            float al0 = __expf(m0 - mn0);
            float p0  = __expf(s0 - mn0);
            m0 = mn0; l0 = l0 * al0 + p0;
            float mn1 = fmaxf(m1, s1);
            float al1 = __expf(m1 - mn1);
            float p1  = __expf(s1 - mn1);
            m1 = mn1; l1 = l1 * al1 + p1;
            #pragma unroll
            for (int d = 0; d < 32; ++d) {
                float vv = Vs[j][d];
                acc0[d] = acc0[d] * al0 + p0 * vv;
                acc1[d] = acc1[d] * al1 + p1 * vv;
            }
        }
        __syncthreads();
    }
    const float inv0 = 1.f / l0, inv1 = 1.f / l1;
    float* o0 = Aout + (size_t)r0 * DIM + h * HD + half * 32;
    float* o1 = Aout + (size_t)r1 * DIM + h * HD + half * 32;
    #pragma unroll
    for (int d = 0; d < 32; ++d) {
        o0[d] = acc0[d] * inv0;
        o1[d] = acc1[d] * inv1;
    }
}

// ---------------------------------------------------------------------------
// Combine: y[.., 0:32] = a1 - lam*a2 ; y[.., 32:64] = a1 + lam*a2
// ---------------------------------------------------------------------------
__global__ __launch_bounds__(256) void combine_kernel(
    const float* __restrict__ A, const float* __restrict__ lambda_p,
    float* __restrict__ Y) {
    const int idx = blockIdx.x * 256 + threadIdx.x;
    const int c = idx & (DIM - 1);
    const int s = idx >> 10;
    const int hh = c >> 6;
    const int d = c & 63;
    const float* base = A + (size_t)s * DIM + hh * HD;
    const float lam = lambda_p[hh];
    float y;
    if (d < 32) y = base[d]      - lam * base[d + 32];
    else        y = base[d - 32] + lam * base[d];
    Y[idx] = y;
}

// ---------------------------------------------------------------------------
// Workspace (22 MB):
//  [ 0, 8)  Qp fp32  -> overlaid by Y fp32 (Qp dead after attention)
//  [ 8,10)  Kp   [10,12) Vp   [12,14) Gp
//  [14,22)  Ao fp32
//  Small: qg/lambda read directly (fp32 proven by round-6 probe).
// ---------------------------------------------------------------------------
extern "C" void kernel_launch(void* const* d_in, const int* in_sizes, int n_in,
                              void* d_out, int out_size, void* d_ws, size_t ws_size,
                              hipStream_t stream) {
    const float* x  = (const float*)d_in[0];
    const float* Wq = (const float*)d_in[1];
    const float* Wk = (const float*)d_in[2];
    const float* Wv = (const float*)d_in[3];
    const float* Wg = (const float*)d_in[4];
    const float* Wo = (const float*)d_in[5];
    const float* qg = (const float*)d_in[6];
    const float* lp = (const float*)d_in[7];
    float* out = (float*)d_out;   // fp32 output (verified round 7)

    char* ws = (char*)d_ws;
    float* Qp  = (float*)(ws);
    float* KVG = (float*)(ws + (8u  << 20));
    float* Kp  = KVG;
    float* Vp  = KVG + (size_t)S_LEN * KVDIM;
    float* Gp  = KVG + (size_t)2 * S_LEN * KVDIM;
    float* Ao  = (float*)(ws + (14u << 20));
    float* Y   = (float*)ws;      // overlays dead Qp

    // 1. Projections (tiled fp32 GEMMs)
    gemm_nt<<<dim3(DIM/64, S_LEN/64), 256, 0, stream>>>(x, Wq, Qp, S_LEN, DIM, DIM);
    gemm_kvg<<<dim3(12, S_LEN/64), 256, 0, stream>>>(x, Wk, Wv, Wg, KVG);
    // 2. RMSNorm + rotary + gate
    postproc<<<dim3(S_LEN, NH + 2*NKVH), 64, 0, stream>>>(Qp, Kp, Vp, Gp, qg);
    // 3. Dual-half flash attention
    attn_kernel<<<dim3(64, NKVH, 2), 64, 0, stream>>>(Qp, Kp, Vp, Ao);
    // 4. Lambda combine (Y overlays dead Qp)
    combine_kernel<<<dim3(S_LEN * DIM / 256), 256, 0, stream>>>(Ao, lp, Y);
    // 5. Output projection -> fp32 out
    gemm_nt<<<dim3(DIM/64, S_LEN/64), 256, 0, stream>>>(Y, Wo, out, S_LEN, DIM, DIM);
}

// Round 9
// 769.022 us; speedup vs baseline: 31.3098x; 1.6801x over previous
//
#include <hip/hip_runtime.h>
#include <hip/hip_bf16.h>
#include <math.h>

#define S_LEN 2048
#define DIM   1024
#define NH    16
#define NKVH  4
#define HD    64
#define KVDIM 256
#define NEG_BIG (-1e30f)

typedef __hip_bfloat16 bf16;

// ---------------------------------------------------------------------------
// GEMM: C[M,N] = A[M,K] * B[N,K]^T (unchanged from round 8, verified)
// ---------------------------------------------------------------------------
__global__ __launch_bounds__(256) void gemm_nt(
    const float* __restrict__ A, const float* __restrict__ B,
    float* __restrict__ C, int M, int N, int K) {
    __shared__ float As[64][36];
    __shared__ float Bs[64][36];
    const int tid = threadIdx.x;
    const int bm = blockIdx.y * 64;
    const int bn = blockIdx.x * 64;
    const int lr = tid >> 2;
    const int lc = (tid & 3) << 3;
    const int ty = tid >> 4;
    const int tx = tid & 15;
    float acc[4][4] = {};
    const float* ap = A + (size_t)(bm + lr) * K + lc;
    const float* bp = B + (size_t)(bn + lr) * K + lc;
    for (int k0 = 0; k0 < K; k0 += 32) {
        float4 a0 = *(const float4*)(ap + k0);
        float4 a1 = *(const float4*)(ap + k0 + 4);
        float4 b0 = *(const float4*)(bp + k0);
        float4 b1 = *(const float4*)(bp + k0 + 4);
        *(float4*)&As[lr][lc]     = a0;
        *(float4*)&As[lr][lc + 4] = a1;
        *(float4*)&Bs[lr][lc]     = b0;
        *(float4*)&Bs[lr][lc + 4] = b1;
        __syncthreads();
        #pragma unroll
        for (int kk = 0; kk < 32; kk += 4) {
            float4 a[4], b[4];
            #pragma unroll
            for (int i = 0; i < 4; ++i) a[i] = *(const float4*)&As[ty + 16*i][kk];
            #pragma unroll
            for (int j = 0; j < 4; ++j) b[j] = *(const float4*)&Bs[tx + 16*j][kk];
            #pragma unroll
            for (int i = 0; i < 4; ++i)
                #pragma unroll
                for (int j = 0; j < 4; ++j)
                    acc[i][j] += a[i].x*b[j].x + a[i].y*b[j].y +
                                 a[i].z*b[j].z + a[i].w*b[j].w;
        }
        __syncthreads();
    }
    #pragma unroll
    for (int i = 0; i < 4; ++i) {
        const int row = bm + ty + 16*i;
        #pragma unroll
        for (int j = 0; j < 4; ++j)
            C[(size_t)row * N + bn + tx + 16*j] = acc[i][j];
    }
}

__global__ __launch_bounds__(256) void gemm_kvg(
    const float* __restrict__ A, const float* __restrict__ B0,
    const float* __restrict__ B1, const float* __restrict__ B2,
    float* __restrict__ C) {
    __shared__ float As[64][36];
    __shared__ float Bs[64][36];
    const int tid = threadIdx.x;
    const int w  = blockIdx.x >> 2;
    const int bn = (blockIdx.x & 3) * 64;
    const int bm = blockIdx.y * 64;
    const float* B = (w == 0) ? B0 : (w == 1) ? B1 : B2;
    float* Cw = C + (size_t)w * S_LEN * KVDIM;
    const int K = DIM, N = KVDIM;
    const int lr = tid >> 2;
    const int lc = (tid & 3) << 3;
    const int ty = tid >> 4;
    const int tx = tid & 15;
    float acc[4][4] = {};
    const float* ap = A + (size_t)(bm + lr) * K + lc;
    const float* bp = B + (size_t)(bn + lr) * K + lc;
    for (int k0 = 0; k0 < K; k0 += 32) {
        float4 a0 = *(const float4*)(ap + k0);
        float4 a1 = *(const float4*)(ap + k0 + 4);
        float4 b0 = *(const float4*)(bp + k0);
        float4 b1 = *(const float4*)(bp + k0 + 4);
        *(float4*)&As[lr][lc]     = a0;
        *(float4*)&As[lr][lc + 4] = a1;
        *(float4*)&Bs[lr][lc]     = b0;
        *(float4*)&Bs[lr][lc + 4] = b1;
        __syncthreads();
        #pragma unroll
        for (int kk = 0; kk < 32; kk += 4) {
            float4 a[4], b[4];
            #pragma unroll
            for (int i = 0; i < 4; ++i) a[i] = *(const float4*)&As[ty + 16*i][kk];
            #pragma unroll
            for (int j = 0; j < 4; ++j) b[j] = *(const float4*)&Bs[tx + 16*j][kk];
            #pragma unroll
            for (int i = 0; i < 4; ++i)
                #pragma unroll
                for (int j = 0; j < 4; ++j)
                    acc[i][j] += a[i].x*b[j].x + a[i].y*b[j].y +
                                 a[i].z*b[j].z + a[i].w*b[j].w;
        }
        __syncthreads();
    }
    #pragma unroll
    for (int i = 0; i < 4; ++i) {
        const int row = bm + ty + 16*i;
        #pragma unroll
        for (int j = 0; j < 4; ++j)
            Cw[(size_t)row * N + bn + tx + 16*j] = acc[i][j];
    }
}

// ---------------------------------------------------------------------------
// Postproc (unchanged, verified)
// ---------------------------------------------------------------------------
__device__ __forceinline__ void rms_rotary(float* p, int s, int lane, float gain) {
    float x = p[lane];
    float ss = x * x;
    #pragma unroll
    for (int o = 32; o > 0; o >>= 1) ss += __shfl_xor(ss, o);
    float n = x * rsqrtf(ss * (1.0f/64.0f) + 1.1920928955078125e-7f);
    float other = __shfl_xor(n, 32);
    int i = lane & 31;
    float af  = (float)(((double)(2*i) / 64.0) * 3.14159265358979323846);
    float ang = (float)s * af;
    float radius = 1.0f / (1.0f + 0.01f * (float)s);
    float c  = radius * (float)cos((double)ang);
    float sn = radius * (float)sin((double)ang);
    float out = n * c + ((lane < 32) ? other * sn : -other * sn);
    p[lane] = out * gain;
}

__global__ __launch_bounds__(64) void postproc(
    float* __restrict__ Qp, float* __restrict__ Kp, float* __restrict__ Vp,
    const float* __restrict__ Gp, const float* __restrict__ qgain) {
    const int s = blockIdx.x;
    const int unit = blockIdx.y;
    const int lane = threadIdx.x;
    if (unit < NH) {
        rms_rotary(Qp + (size_t)s * DIM + unit * HD, s, lane, qgain[unit]);
    } else if (unit < NH + NKVH) {
        rms_rotary(Kp + (size_t)s * KVDIM + (unit - NH) * HD, s, lane, 1.0f);
    } else {
        const int h = unit - NH - NKVH;
        float* v = Vp + (size_t)s * KVDIM + h * HD;
        const float* g = Gp + (size_t)s * KVDIM + h * HD;
        float gv = g[lane];
        v[lane] = v[lane] / (1.0f + __expf(-gv));
    }
}

// ---------------------------------------------------------------------------
// Flash attention v2: grid (32 qtiles*64rows [heavy first], NH, 2 halves),
// 256 threads = 4 waves. 1 q-row per lane. Split-K: wave w takes k-tiles
// w, w+4, ... with wave-private LDS K/V tiles (no intra-loop barriers),
// two-phase per-tile softmax (one rescale/tile), LDS merge at the end.
// All-finite arithmetic (NEG_BIG sentinel); tile 0 -> wave 0 so row's m is
// always real before merge.
// ---------------------------------------------------------------------------
__global__ void attn_kernel(
    const float* __restrict__ Qp, const float* __restrict__ Kp,
    const float* __restrict__ Vp, float* __restrict__ Aout) {
    __shared__ float lds[9216];           // 4 waves * (K 32x36 + V 32x36)
    __shared__ float mbuf[3][64], lbuf[3][64];
    const int qt   = 31 - blockIdx.x;     // heavy q-tiles dispatch first
    const int h    = blockIdx.y;
    const int half = blockIdx.z;
    const int kvh  = h >> 2;
    const int tid  = threadIdx.x;
    const int w    = tid >> 6;            // wave 0..3
    const int lane = tid & 63;
    const int r    = qt * 64 + lane;      // this lane's q row
    float* KsW = &lds[w * 2304];
    float* VsW = KsW + 1152;

    float q[32], acc[32] = {};
    {
        const float* qp = Qp + (size_t)r * DIM + h * HD + half * 32;
        #pragma unroll
        for (int d = 0; d < 32; d += 4) *(float4*)&q[d] = *(const float4*)(qp + d);
    }
    float m = NEG_BIG, l = 0.f;
    const float scale = 0.17677669529663687f;  // 1/sqrt(32)
    const int srow = lane >> 1;
    const int scol = (lane & 1) * 16;
    const int nkt = 2 * qt + 2;           // key tiles covering rows <= qt*64+63

    for (int kb = w; kb < nkt; kb += 4) {
        // stage this wave's K/V tile (wave-synchronous, no barrier needed)
        {
            const size_t base = (size_t)(kb * 32 + srow) * KVDIM + kvh * HD + half * 32 + scol;
            const float* kp = Kp + base;
            const float* vp = Vp + base;
            float* kd = &KsW[srow * 36 + scol];
            float* vd = &VsW[srow * 36 + scol];
            #pragma unroll
            for (int c = 0; c < 16; c += 4) {
                *(float4*)(kd + c) = *(const float4*)(kp + c);
                *(float4*)(vd + c) = *(const float4*)(vp + c);
            }
        }
        // phase 1: 32 scores into registers, causal mask, tile max
        float s[32];
        const int j0 = kb * 32;
        #pragma unroll
        for (int j = 0; j < 32; ++j) {
            const float* kr = &KsW[j * 36];
            float a = 0.f;
            #pragma unroll
            for (int d = 0; d < 32; d += 4) {
                float4 kv = *(const float4*)(kr + d);
                a += q[d]*kv.x + q[d+1]*kv.y + q[d+2]*kv.z + q[d+3]*kv.w;
            }
            s[j] = (j0 + j > r) ? NEG_BIG : a * scale;
        }
        float tm = s[0];
        #pragma unroll
        for (int j = 1; j < 32; ++j) tm = fmaxf(tm, s[j]);
        // phase 2: single rescale per tile, then 1-FMA/dim PV accumulate
        const float mn = fmaxf(m, tm);
        const float al = __expf(m - mn);
        m = mn; l *= al;
        #pragma unroll
        for (int d = 0; d < 32; ++d) acc[d] *= al;
        #pragma unroll
        for (int j = 0; j < 32; ++j) {
            const float p = __expf(s[j] - mn);
            l += p;
            const float* vr = &VsW[j * 36];
            #pragma unroll
            for (int d = 0; d < 32; d += 4) {
                float4 vv = *(const float4*)(vr + d);
                acc[d]   += p * vv.x;
                acc[d+1] += p * vv.y;
                acc[d+2] += p * vv.z;
                acc[d+3] += p * vv.w;
            }
        }
    }

    // merge the 4 waves' partial flash states (stride 33 -> conflict-free)
    __syncthreads();
    if (w > 0) {
        float* dst = &lds[(w - 1) * 64 * 33 + lane * 33];
        #pragma unroll
        for (int d = 0; d < 32; ++d) dst[d] = acc[d];
        mbuf[w - 1][lane] = m;
        lbuf[w - 1][lane] = l;
    }
    __syncthreads();
    if (w == 0) {
        #pragma unroll
        for (int p = 0; p < 3; ++p) {
            const float mm = mbuf[p][lane];
            const float ll = lbuf[p][lane];
            const float mn = fmaxf(m, mm);
            const float a0 = __expf(m - mn);
            const float a1 = __expf(mm - mn);
            m = mn;
            l = l * a0 + ll * a1;
            const float* src = &lds[p * 64 * 33 + lane * 33];
            #pragma unroll
            for (int d = 0; d < 32; ++d) acc[d] = acc[d] * a0 + src[d] * a1;
        }
        const float inv = 1.f / l;
        float* o = Aout + (size_t)r * DIM + h * HD + half * 32;
        #pragma unroll
        for (int d = 0; d < 32; ++d) o[d] = acc[d] * inv;
    }
}

// ---------------------------------------------------------------------------
// Combine (unchanged, verified)
// ---------------------------------------------------------------------------
__global__ __launch_bounds__(256) void combine_kernel(
    const float* __restrict__ A, const float* __restrict__ lambda_p,
    float* __restrict__ Y) {
    const int idx = blockIdx.x * 256 + threadIdx.x;
    const int c = idx & (DIM - 1);
    const int s = idx >> 10;
    const int hh = c >> 6;
    const int d = c & 63;
    const float* base = A + (size_t)s * DIM + hh * HD;
    const float lam = lambda_p[hh];
    float y;
    if (d < 32) y = base[d]      - lam * base[d + 32];
    else        y = base[d - 32] + lam * base[d];
    Y[idx] = y;
}

// ---------------------------------------------------------------------------
extern "C" void kernel_launch(void* const* d_in, const int* in_sizes, int n_in,
                              void* d_out, int out_size, void* d_ws, size_t ws_size,
                              hipStream_t stream) {
    const float* x  = (const float*)d_in[0];
    const float* Wq = (const float*)d_in[1];
    const float* Wk = (const float*)d_in[2];
    const float* Wv = (const float*)d_in[3];
    const float* Wg = (const float*)d_in[4];
    const float* Wo = (const float*)d_in[5];
    const float* qg = (const float*)d_in[6];
    const float* lp = (const float*)d_in[7];
    float* out = (float*)d_out;

    char* ws = (char*)d_ws;
    float* Qp  = (float*)(ws);
    float* KVG = (float*)(ws + (8u  << 20));
    float* Kp  = KVG;
    float* Vp  = KVG + (size_t)S_LEN * KVDIM;
    float* Gp  = KVG + (size_t)2 * S_LEN * KVDIM;
    float* Ao  = (float*)(ws + (14u << 20));
    float* Y   = (float*)ws;      // overlays dead Qp

    gemm_nt<<<dim3(DIM/64, S_LEN/64), 256, 0, stream>>>(x, Wq, Qp, S_LEN, DIM, DIM);
    gemm_kvg<<<dim3(12, S_LEN/64), 256, 0, stream>>>(x, Wk, Wv, Wg, KVG);
    postproc<<<dim3(S_LEN, NH + 2*NKVH), 64, 0, stream>>>(Qp, Kp, Vp, Gp, qg);
    attn_kernel<<<dim3(32, NH, 2), 256, 0, stream>>>(Qp, Kp, Vp, Ao);
    combine_kernel<<<dim3(S_LEN * DIM / 256), 256, 0, stream>>>(Ao, lp, Y);
    gemm_nt<<<dim3(DIM/64, S_LEN/64), 256, 0, stream>>>(Y, Wo, out, S_LEN, DIM, DIM);
}